// Round 4
// baseline (123.573 us; speedup 1.0000x reference)
//
#include <hip/hip_runtime.h>

// FactorizedEmbedding: out[m,:] = embed_vocab[x[m],:] @ embed_hidden
//   x: [16384] int, ev: [128000,128] f32, eh: [128,1024] f32, out: [16384,1024] f32
//
// Split-bf16 (truncation hi + exact-residual lo, round-2-proven) MFMA,
// 3 products: ah*bh + ah*bl + al*bh.
// Prep kernels convert everything once into d_ws (stage-major, pre-swizzled):
//   wsB: eh^T [s:4][n:1024][16 u32] bf16 hi/lo      (2 x 256 KB)
//   wsA: gathered ev rows [s:4][m:16384][16 u32]    (2 x 4 MB)
// Main kernel: pure global_load_lds staging (each issue = contiguous 1 KB),
// 2-phase dbuf pipeline, EXPLICIT s_waitcnt(0) before every barrier (race fix),
// 16x16x32 bf16 MFMA via earlyclobber asm (D cannot alias A/B — alloc-safe).

using f32x4 = __attribute__((ext_vector_type(4))) float;
using i32x4 = __attribute__((ext_vector_type(4))) int;
typedef unsigned int u32;

constexpr int EMB = 128;
constexpr int HID = 1024;

// 8 fp32 -> packed bf16 hi (truncate) + bf16 lo (truncate of exact residual).
__device__ inline void cvt8(const float f[8], i32x4& hi, i32x4& lo) {
    u32 h[8], l[8];
#pragma unroll
    for (int e = 0; e < 8; ++e) {
        u32 fb = __float_as_uint(f[e]);
        u32 hb = fb & 0xFFFF0000u;               // bf16 hi (truncate)
        float r = f[e] - __uint_as_float(hb);    // exact residual
        u32 lb = __float_as_uint(r) & 0xFFFF0000u;
        h[e] = hb; l[e] = lb;
    }
#pragma unroll
    for (int p = 0; p < 4; ++p) {
        hi[p] = (int)((h[2*p] >> 16) | h[2*p+1]);   // elem 2p low half, 2p+1 high
        lo[p] = (int)((l[2*p] >> 16) | l[2*p+1]);
    }
}

// Earlyclobber, untied C: guarantees D does not alias A/B (HW requirement);
// D = A*B + C with C a separate register tuple is the legal 3-address form.
__device__ inline f32x4 mfma_bf16(i32x4 a, i32x4 b, f32x4 c) {
    f32x4 d;
    asm volatile("v_mfma_f32_16x16x32_bf16 %0, %1, %2, %3"
                 : "=&v"(d) : "v"(a), "v"(b), "v"(c));
    return d;
}

__device__ inline void gload16(const u32* src, u32* ldsdst) {
    __builtin_amdgcn_global_load_lds(
        (const __attribute__((address_space(1))) u32*)src,
        (__attribute__((address_space(3))) u32*)ldsdst, 16, 0, 0);
}

// ---- prep 1: eh [128][1024] -> wsB [s][n][16 u32], swizzled slot gs = (k8&3)^((n>>1)&3)
__global__ void prep_eh(const float* __restrict__ eh, u32* __restrict__ wsBh,
                        u32* __restrict__ wsBl) {
    const int t  = blockIdx.x * 256 + threadIdx.x;   // 0..16383
    const int n  = t >> 4, k8 = t & 15;
    float f[8];
#pragma unroll
    for (int j = 0; j < 8; ++j) f[j] = eh[(k8*8 + j)*HID + n];
    i32x4 hi, lo; cvt8(f, hi, lo);
    const int s = k8 >> 2, gs = (k8 & 3) ^ ((n >> 1) & 3);
    const int off = (s*HID + n)*16 + gs*4;
    *(i32x4*)(wsBh + off) = hi;
    *(i32x4*)(wsBl + off) = lo;
}

// ---- prep 2: gather ev[x[m]] -> wsA [s][m][16 u32], swizzled
__global__ void prep_ev(const int* __restrict__ x, const float* __restrict__ ev,
                        u32* __restrict__ wsAh, u32* __restrict__ wsAl, int M) {
    const int t = blockIdx.x * 256 + threadIdx.x;    // M*16 threads
    const int m = t >> 4, k8 = t & 15;
    const long id = x[m];
    const float* src = ev + id * EMB + k8*8;
    float f[8];
    *(float4*)(f)     = *(const float4*)(src);
    *(float4*)(f + 4) = *(const float4*)(src + 4);
    i32x4 hi, lo; cvt8(f, hi, lo);
    const int s = k8 >> 2, gs = (k8 & 3) ^ ((m >> 1) & 3);
    const long off = ((long)s*M + m)*16 + gs*4;
    *(i32x4*)(wsAh + off) = hi;
    *(i32x4*)(wsAl + off) = lo;
}

// ---- main: 128x128 tile, 4 waves 2x2 (64x64 each), K in 4 stages of 32.
__global__ __launch_bounds__(256, 2)
void femb_main(const u32* __restrict__ wsAh, const u32* __restrict__ wsAl,
               const u32* __restrict__ wsBh, const u32* __restrict__ wsBl,
               float* __restrict__ out, int mtiles, int M)
{
    __shared__ __align__(16) u32 lds[2][4][2048];    // [buf][Ah,Al,Bh,Bl][8KB]

    const int tid  = threadIdx.x;
    const int lane = tid & 63, wid = tid >> 6;
    const int bid  = blockIdx.x;
    const int mt   = bid % mtiles;       // blocks sharing A-tile: bid mod 8 equal -> same XCD
    const int nt   = bid / mtiles;
    const long m0  = (long)mt * 128, n0 = (long)nt * 128;
    const int wm   = wid >> 1, wn = wid & 1;
    const int rl   = lane & 15, g = lane >> 4;

    // gload_lds: LDS dest = wave-uniform base + lane*16B (linear);
    // lane covers row = wid*32 + j*16 + (lane>>2), slot = lane&3.
    // Global src per-lane: stage-major ws makes each issue contiguous 1 KB.
    const int row_ = wid*32 + (lane >> 2);
    const int gr_  = lane & 3;

    f32x4 acc[4][4];
#pragma unroll
    for (int i = 0; i < 4; ++i)
#pragma unroll
        for (int j = 0; j < 4; ++j) acc[i][j] = (f32x4){0.f, 0.f, 0.f, 0.f};

    auto stage = [&](int s, int buf) {
#pragma unroll
        for (int j = 0; j < 2; ++j) {
            const int  r  = row_ + j*16;
            const int  lo = wid*512 + j*256;                  // u32 LDS offset (uniform)
            const long ao = ((long)s*M   + m0 + r)*16 + gr_*4;
            const long bo = ((long)s*HID + n0 + r)*16 + gr_*4;
            gload16(wsAh + ao, &lds[buf][0][lo]);
            gload16(wsAl + ao, &lds[buf][1][lo]);
            gload16(wsBh + bo, &lds[buf][2][lo]);
            gload16(wsBl + bo, &lds[buf][3][lo]);
        }
    };

    auto compute = [&](int buf) {
        i32x4 bh[4], bl[4];
#pragma unroll
        for (int nf = 0; nf < 4; ++nf) {
            const int nr  = wn*64 + nf*16 + rl;
            const int off = nr*16 + ((g ^ ((nr >> 1) & 3)) << 2);
            bh[nf] = *(const i32x4*)&lds[buf][2][off];
            bl[nf] = *(const i32x4*)&lds[buf][3][off];
        }
#pragma unroll
        for (int mf = 0; mf < 4; ++mf) {
            const int mr  = wm*64 + mf*16 + rl;
            const int off = mr*16 + ((g ^ ((mr >> 1) & 3)) << 2);
            const i32x4 ah = *(const i32x4*)&lds[buf][0][off];
            const i32x4 al = *(const i32x4*)&lds[buf][1][off];
#pragma unroll
            for (int nf = 0; nf < 4; ++nf) {
                acc[mf][nf] = mfma_bf16(ah, bh[nf], acc[mf][nf]);
                acc[mf][nf] = mfma_bf16(ah, bl[nf], acc[mf][nf]);
                acc[mf][nf] = mfma_bf16(al, bh[nf], acc[mf][nf]);
            }
        }
    };

    stage(0, 0);
    for (int s = 0; s < 4; ++s) {
        __builtin_amdgcn_s_waitcnt(0);   // EXPLICIT drain: stage(s) data landed.
        __syncthreads();                 // (do not rely on compiler's pre-barrier drain)
        if (s < 3) stage(s + 1, (s + 1) & 1);   // prefetch overlaps compute(s)
        compute(s & 1);
    }

    // epilogue: C/D layout col = lane&15, row = (lane>>4)*4 + j  [m89/m91]
#pragma unroll
    for (int mf = 0; mf < 4; ++mf)
#pragma unroll
        for (int j = 0; j < 4; ++j) {
            const long row = m0 + wm*64 + mf*16 + g*4 + j;
            float* dst = out + row * HID + n0 + wn*64 + rl;
#pragma unroll
            for (int nf = 0; nf < 4; ++nf) dst[nf * 16] = acc[mf][nf][j];
        }
}

extern "C" void kernel_launch(void* const* d_in, const int* in_sizes, int n_in,
                              void* d_out, int out_size, void* d_ws, size_t ws_size,
                              hipStream_t stream) {
    const int*   x   = (const int*)d_in[0];
    const float* ev  = (const float*)d_in[1];
    const float* eh  = (const float*)d_in[2];
    float*       out = (float*)d_out;

    const int M      = in_sizes[0];          // 16384
    const int mtiles = M / 128;              // 128

    // ws carve (u32 units): Bh 256KB | Bl 256KB | Ah 4MB | Al 4MB
    u32* wsBh = (u32*)d_ws;
    u32* wsBl = wsBh + (size_t)HID*64;
    u32* wsAh = wsBl + (size_t)HID*64;
    u32* wsAl = wsAh + (size_t)M*64;
    if (ws_size < (size_t)(2*HID*64 + 2*(size_t)M*64) * 4) return;

    prep_eh<<<HID*16/256, 256, 0, stream>>>(eh, wsBh, wsBl);
    prep_ev<<<M*16/256, 256, 0, stream>>>(x, ev, wsAh, wsAl, M);
    femb_main<<<mtiles * (HID/128), 256, 0, stream>>>(wsAh, wsAl, wsBh, wsBl,
                                                      out, mtiles, M);
}